// Round 9
// baseline (862.707 us; speedup 1.0000x reference)
//
#include <hip/hip_runtime.h>

#define CIN 128
#define COUT 64
#define NBSH 8                 // nodes per bucket = 256
#define CS 512                 // count-matrix stride (nbk, nchunk <= 512)
#define CHUNK 4096             // edges per chunk
#define BMAX 5120              // per-bucket slab capacity (mean 4096, sigma ~64)

typedef unsigned int u32;
typedef unsigned short u16;
typedef __attribute__((ext_vector_type(8))) __bf16 bf16x8;
typedef __attribute__((ext_vector_type(4))) float f32x4;

union B8 { u32 u[4]; uint4 q; bf16x8 v; };

__device__ __forceinline__ u16 bf16rne(float x) {
    u32 u = __float_as_uint(x);
    u += 0x7fffu + ((u >> 16) & 1u);
    return (u16)(u >> 16);
}

// ---------------- chunk-local bucket sort: all global writes dense ----------------
// Block = chunk of 4096 edges. LDS bucket-sort by dst>>8; write sorted chunk
// contiguously to tmp; emit per-chunk count row + row-offset row (coalesced).

__global__ __launch_bounds__(512) void bucket_local_kernel(
    const int* __restrict__ src, const int* __restrict__ dst,
    int* __restrict__ tmp, int* __restrict__ cnt, int* __restrict__ rowoff,
    int E) {
    __shared__ int hist[CS];
    __shared__ int scn[CS];
    __shared__ int lofs[CS];
    __shared__ int lcur[CS];
    __shared__ int stage[CHUNK];
    const int t = threadIdx.x;
    const int c = blockIdx.x;
    const int e0 = c * CHUNK;
    const int m = (E - e0 < CHUNK) ? (E - e0) : CHUNK;

    hist[t] = 0; lcur[t] = 0;
    __syncthreads();

    int pk[8], bb[8];
    #pragma unroll
    for (int j = 0; j < 8; ++j) {
        int i = t + j * 512;
        bool ok = i < m;
        int d = ok ? __builtin_nontemporal_load(&dst[e0 + i]) : 0;
        int s = ok ? __builtin_nontemporal_load(&src[e0 + i]) : 0;
        pk[j] = (s << NBSH) | (d & ((1 << NBSH) - 1));
        bb[j] = d >> NBSH;
        if (ok) atomicAdd(&hist[bb[j]], 1);
    }
    __syncthreads();

    int myv = hist[t];
    scn[t] = myv;
    __syncthreads();
    #pragma unroll
    for (int ofs = 1; ofs < CS; ofs <<= 1) {
        int u = (t >= ofs) ? scn[t - ofs] : 0;
        __syncthreads();
        scn[t] += u;
        __syncthreads();
    }
    lofs[t] = scn[t] - myv;
    cnt[c * CS + t] = myv;
    rowoff[c * CS + t] = scn[t] - myv;
    __syncthreads();

    #pragma unroll
    for (int j = 0; j < 8; ++j) {
        int i = t + j * 512;
        if (i < m) {
            int b = bb[j];
            int pos = lofs[b] + atomicAdd(&lcur[b], 1);
            stage[pos] = pk[j];
        }
    }
    __syncthreads();
    for (int i = t; i < m; i += 512) tmp[e0 + i] = stage[i];
}

// ---------------- deg2: per-bucket slab compaction + degree histogram ----------------
// Block = bucket. One thread per chunk copies its run into the bucket's dense
// slab esrcB[k*BMAX ..] (single-XCD writes, lines assemble in local L2),
// counting low-byte (node) occupancy in LDS -> dinv.

__global__ __launch_bounds__(512) void deg2_kernel(
    const int* __restrict__ tmp, const int* __restrict__ cnt,
    const int* __restrict__ rowoff, int* __restrict__ esrcB,
    int* __restrict__ btotal, float* __restrict__ dinv, int n, int nchunk) {
    __shared__ int scn[CS];
    __shared__ int hist[1 << NBSH];
    const int k = blockIdx.x;
    const int t = threadIdx.x;

    int myc = (t < nchunk) ? cnt[t * CS + k] : 0;
    int ro  = (t < nchunk) ? rowoff[t * CS + k] : 0;
    scn[t] = myc;
    if (t < (1 << NBSH)) hist[t] = 0;
    __syncthreads();
    #pragma unroll
    for (int ofs = 1; ofs < CS; ofs <<= 1) {
        int u = (t >= ofs) ? scn[t - ofs] : 0;
        __syncthreads();
        scn[t] += u;
        __syncthreads();
    }
    const int db = scn[t] - myc;            // this chunk's dest offset in slab
    const int total = scn[CS - 1];

    if (t < nchunk && myc > 0) {
        const int sb = t * CHUNK + ro;
        for (int j = 0; j < myc; ++j) {
            int idx = db + j;
            if (idx < BMAX) {
                int e = __builtin_nontemporal_load(&tmp[sb + j]);
                esrcB[(size_t)k * BMAX + idx] = e;
                atomicAdd(&hist[e & ((1 << NBSH) - 1)], 1);
            }
        }
    }
    __syncthreads();
    if (t == 0) btotal[k] = (total < BMAX) ? total : BMAX;
    if (t < (1 << NBSH)) {
        int v = (k << NBSH) + t;
        if (v < n) dinv[v] = rsqrtf(1.0f + (float)hist[t]);
    }
}

// ---------------- H_s = (X @ W + b) * dinv[row] via bf16 MFMA, stored bf16 ----------------

__global__ __launch_bounds__(256) void gemm_kernel(
    const float* __restrict__ X, const float* __restrict__ W,
    const float* __restrict__ bias, const float* __restrict__ dinv,
    u16* __restrict__ Hs, int n) {
    __shared__ __align__(16) u16 Wt[64 * 128];   // [c][k] swizzled, 16 KB
    const int t = threadIdx.x;
    const int lane = t & 63;
    const int q = lane >> 4;
    const int cl = lane & 15;
    const int row0 = blockIdx.x * 128 + (t >> 6) * 32;

    for (int i = t; i < CIN * COUT; i += 256) {
        int k = i >> 6, c = i & 63;
        int byte = (c << 8) + (k << 1);
        byte ^= (c & 7) << 4;
        *(u16*)((char*)Wt + byte) = bf16rne(W[i]);
    }
    __syncthreads();

    f32x4 acc[2][4];
    #pragma unroll
    for (int mt = 0; mt < 2; ++mt)
        #pragma unroll
        for (int nt = 0; nt < 4; ++nt)
            acc[mt][nt] = (f32x4){0.0f, 0.0f, 0.0f, 0.0f};

    #pragma unroll
    for (int kk = 0; kk < 4; ++kk) {
        bf16x8 a[2], bfr[4];
        #pragma unroll
        for (int mt = 0; mt < 2; ++mt) {
            int row = row0 + mt * 16 + cl;
            const float* xp = X + (size_t)(row < n ? row : 0) * CIN + kk * 32 + q * 8;
            f32x4 x0 = __builtin_nontemporal_load((const f32x4*)xp);
            f32x4 x1 = __builtin_nontemporal_load((const f32x4*)(xp + 4));
            B8 pk;
            pk.u[0] = (u32)bf16rne(x0[0]) | ((u32)bf16rne(x0[1]) << 16);
            pk.u[1] = (u32)bf16rne(x0[2]) | ((u32)bf16rne(x0[3]) << 16);
            pk.u[2] = (u32)bf16rne(x1[0]) | ((u32)bf16rne(x1[1]) << 16);
            pk.u[3] = (u32)bf16rne(x1[2]) | ((u32)bf16rne(x1[3]) << 16);
            a[mt] = pk.v;
        }
        #pragma unroll
        for (int nt = 0; nt < 4; ++nt) {
            int c = nt * 16 + cl;
            int byte = (c << 8) + ((kk * 32 + q * 8) << 1);
            byte ^= (c & 7) << 4;
            B8 pk;
            pk.q = *(const uint4*)((const char*)Wt + byte);
            bfr[nt] = pk.v;
        }
        #pragma unroll
        for (int mt = 0; mt < 2; ++mt)
            #pragma unroll
            for (int nt = 0; nt < 4; ++nt)
                acc[mt][nt] = __builtin_amdgcn_mfma_f32_16x16x32_bf16(
                    a[mt], bfr[nt], acc[mt][nt], 0, 0, 0);
    }

    #pragma unroll
    for (int mt = 0; mt < 2; ++mt) {
        const int rbase = row0 + mt * 16 + q * 4;
        float dv[4];
        #pragma unroll
        for (int r = 0; r < 4; ++r)
            dv[r] = (rbase + r < n) ? dinv[rbase + r] : 0.0f;
        #pragma unroll
        for (int nt = 0; nt < 4; ++nt) {
            const int col = nt * 16 + cl;
            const float bc = bias[col];
            #pragma unroll
            for (int r = 0; r < 4; ++r) {
                int row = rbase + r;
                if (row < n)
                    Hs[(size_t)row * COUT + col] = bf16rne((acc[mt][nt][r] + bc) * dv[r]);
            }
        }
    }
}

// ---------------- bucket gather: LDS fp32 accumulator, no per-node CSR ----------------
// Block = bucket (256 nodes). acc[256][66] fp32 in dynamic LDS (67.6 KB).
// 8 waves stream the bucket slab; each wave: 4 edges/iter x 16 lanes x 4ch,
// ds_add_f32 into acc. Epilogue: + self term, *dinv, relu, dense nt store.

__global__ __launch_bounds__(512) void bucketgather_kernel(
    const u16* __restrict__ Hs, const int* __restrict__ esrcB,
    const int* __restrict__ btotal, const float* __restrict__ dinv,
    float* __restrict__ out, int n) {
    extern __shared__ float acc[];   // [256][66]
    const int k = blockIdx.x;
    const int t = threadIdx.x;
    const int lane = t & 63;
    const int wv = t >> 6;           // 8 waves
    const int slot = lane >> 4;
    const int cg = lane & 15;

    for (int i = t; i < 256 * 66; i += 512) acc[i] = 0.0f;
    __syncthreads();

    const int total = btotal[k];
    const size_t base = (size_t)k * BMAX;

    for (int j0 = wv * 64; j0 < total; j0 += 512) {
        int my = j0 + lane;
        int e_l = (my < total) ? esrcB[base + my] : 0;
        int m = (total - j0 < 64) ? (total - j0) : 64;
        for (int j = 0; j < m; j += 4) {
            int e = __shfl(e_l, j + slot);
            if (j + slot < m) {
                int s = e >> NBSH;
                int l = e & ((1 << NBSH) - 1);
                uint2 h = *(const uint2*)&Hs[(size_t)s * COUT + cg * 4];
                float* ap = &acc[l * 66 + cg * 4];
                atomicAdd(ap + 0, __uint_as_float(h.x << 16));
                atomicAdd(ap + 1, __uint_as_float(h.x & 0xffff0000u));
                atomicAdd(ap + 2, __uint_as_float(h.y << 16));
                atomicAdd(ap + 3, __uint_as_float(h.y & 0xffff0000u));
            }
        }
    }
    __syncthreads();

    // epilogue: 32 rows per iteration (16 threads x 4 ch per row)
    const int rt = t >> 4;
    const int cg2 = t & 15;
    for (int r0 = 0; r0 < 256; r0 += 32) {
        int l = r0 + rt;
        int v = (k << NBSH) + l;
        if (v < n) {
            uint2 h = *(const uint2*)&Hs[(size_t)v * COUT + cg2 * 4];
            float dv = dinv[v];
            const float* ap = &acc[l * 66 + cg2 * 4];
            f32x4 o;
            o[0] = fmaxf((ap[0] + __uint_as_float(h.x << 16)) * dv, 0.0f);
            o[1] = fmaxf((ap[1] + __uint_as_float(h.x & 0xffff0000u)) * dv, 0.0f);
            o[2] = fmaxf((ap[2] + __uint_as_float(h.y << 16)) * dv, 0.0f);
            o[3] = fmaxf((ap[3] + __uint_as_float(h.y & 0xffff0000u)) * dv, 0.0f);
            __builtin_nontemporal_store(o, (f32x4*)&out[(size_t)v * COUT + cg2 * 4]);
        }
    }
}

extern "C" void kernel_launch(void* const* d_in, const int* in_sizes, int n_in,
                              void* d_out, int out_size, void* d_ws, size_t ws_size,
                              hipStream_t stream) {
    const float* X    = (const float*)d_in[0];
    const float* W    = (const float*)d_in[1];
    const float* bias = (const float*)d_in[2];
    const int*   src  = (const int*)d_in[3];
    const int*   dst  = (const int*)d_in[4];
    float* out = (float*)d_out;

    const int n = in_sizes[0] / CIN;
    const int E = in_sizes[3];
    const int nbk = (n + (1 << NBSH) - 1) >> NBSH;       // <= 512
    const int nchunk = (E + CHUNK - 1) / CHUNK;          // <= 512

    char* ws = (char*)d_ws;
    size_t o = 0;
    u16*   Hs     = (u16*)(ws + o);   o += (size_t)n * COUT * 2;        // 12.8 MB
    int*   tmp    = (int*)(ws + o);   o += (size_t)nchunk * CHUNK * 4;  // 6.4 MB
    int*   esrcB  = (int*)(ws + o);   o += (size_t)nbk * BMAX * 4;      // 8.0 MB
    int*   cnt    = (int*)(ws + o);   o += (size_t)nchunk * CS * 4;     // 0.8 MB
    int*   rowoff = (int*)(ws + o);   o += (size_t)nchunk * CS * 4;     // 0.8 MB
    float* dinv   = (float*)(ws + o); o += (size_t)n * 4;
    int*   btotal = (int*)(ws + o);   o += CS * 4;

    bucket_local_kernel<<<nchunk, 512, 0, stream>>>(src, dst, tmp, cnt, rowoff, E);
    deg2_kernel<<<nbk, 512, 0, stream>>>(tmp, cnt, rowoff, esrcB, btotal, dinv, n, nchunk);
    gemm_kernel<<<(n + 127) / 128, 256, 0, stream>>>(X, W, bias, dinv, Hs, n);
    bucketgather_kernel<<<nbk, 512, 256 * 66 * 4, stream>>>(Hs, esrcB, btotal, dinv, out, n);
}

// Round 10
// 180.645 us; speedup vs baseline: 4.7757x; 4.7757x over previous
//
#include <hip/hip_runtime.h>

#define CIN 128
#define COUT 64
#define NBSH 8                 // nodes per bucket = 256
#define CS 512                 // count-matrix stride (nbk, nchunk <= 512)
#define CHUNK 4096             // edges per chunk
#define BMAX 5120              // per-bucket edge capacity (mean 4096, sigma ~64)

typedef unsigned int u32;
typedef unsigned short u16;
typedef __attribute__((ext_vector_type(8))) __bf16 bf16x8;
typedef __attribute__((ext_vector_type(4))) float f32x4;

union B8 { u32 u[4]; uint4 q; bf16x8 v; };

__device__ __forceinline__ u16 bf16rne(float x) {
    u32 u = __float_as_uint(x);
    u += 0x7fffu + ((u >> 16) & 1u);
    return (u16)(u >> 16);
}

// ---------------- chunk-local bucket sort: all global writes dense ----------------

__global__ __launch_bounds__(512) void bucket_local_kernel(
    const int* __restrict__ src, const int* __restrict__ dst,
    int* __restrict__ tmp, int* __restrict__ cnt, int* __restrict__ rowoff,
    int E) {
    __shared__ int hist[CS];
    __shared__ int scn[CS];
    __shared__ int lofs[CS];
    __shared__ int lcur[CS];
    __shared__ int stage[CHUNK];
    const int t = threadIdx.x;
    const int c = blockIdx.x;
    const int e0 = c * CHUNK;
    const int m = (E - e0 < CHUNK) ? (E - e0) : CHUNK;

    hist[t] = 0; lcur[t] = 0;
    __syncthreads();

    int pk[8], bb[8];
    #pragma unroll
    for (int j = 0; j < 8; ++j) {
        int i = t + j * 512;
        bool ok = i < m;
        int d = ok ? __builtin_nontemporal_load(&dst[e0 + i]) : 0;
        int s = ok ? __builtin_nontemporal_load(&src[e0 + i]) : 0;
        pk[j] = (s << NBSH) | (d & ((1 << NBSH) - 1));
        bb[j] = d >> NBSH;
        if (ok) atomicAdd(&hist[bb[j]], 1);
    }
    __syncthreads();

    int myv = hist[t];
    scn[t] = myv;
    __syncthreads();
    #pragma unroll
    for (int ofs = 1; ofs < CS; ofs <<= 1) {
        int u = (t >= ofs) ? scn[t - ofs] : 0;
        __syncthreads();
        scn[t] += u;
        __syncthreads();
    }
    lofs[t] = scn[t] - myv;
    cnt[c * CS + t] = myv;
    rowoff[c * CS + t] = scn[t] - myv;
    __syncthreads();

    #pragma unroll
    for (int j = 0; j < 8; ++j) {
        int i = t + j * 512;
        if (i < m) {
            int b = bb[j];
            int pos = lofs[b] + atomicAdd(&lcur[b], 1);
            stage[pos] = pk[j];
        }
    }
    __syncthreads();
    for (int i = t; i < m; i += 512) tmp[e0 + i] = stage[i];
}

// ---------------- degB: per-bucket node histogram -> dinv ----------------
// Quarter-wave (16 lanes) per chunk-run: coalesced-ish run reads, LDS hist.

__global__ __launch_bounds__(512) void degB_kernel(
    const int* __restrict__ tmp, const int* __restrict__ cnt,
    const int* __restrict__ rowoff, float* __restrict__ dinv, int n, int nchunk) {
    __shared__ int cntsh[CS];
    __shared__ int crosh[CS];
    __shared__ int nhist[1 << NBSH];
    const int k = blockIdx.x;
    const int t = threadIdx.x;
    const int qw = t >> 4;
    const int ql = t & 15;

    cntsh[t] = (t < nchunk) ? cnt[t * CS + k] : 0;
    crosh[t] = (t < nchunk) ? rowoff[t * CS + k] : 0;
    if (t < (1 << NBSH)) nhist[t] = 0;
    __syncthreads();

    for (int c = qw; c < nchunk; c += 32) {
        int rc = cntsh[c];
        int sb = c * CHUNK + crosh[c];
        for (int j = ql; j < rc; j += 16) {
            int e = tmp[sb + j];
            atomicAdd(&nhist[e & ((1 << NBSH) - 1)], 1);
        }
    }
    __syncthreads();
    if (t < (1 << NBSH)) {
        int v = (k << NBSH) + t;
        if (v < n) dinv[v] = rsqrtf(1.0f + (float)nhist[t]);
    }
}

// ---------------- H_s = (X @ W + b) * dinv[row] via bf16 MFMA, stored bf16 ----------------

__global__ __launch_bounds__(256) void gemm_kernel(
    const float* __restrict__ X, const float* __restrict__ W,
    const float* __restrict__ bias, const float* __restrict__ dinv,
    u16* __restrict__ Hs, int n) {
    __shared__ __align__(16) u16 Wt[64 * 128];   // [c][k] swizzled, 16 KB
    const int t = threadIdx.x;
    const int lane = t & 63;
    const int q = lane >> 4;
    const int cl = lane & 15;
    const int row0 = blockIdx.x * 128 + (t >> 6) * 32;

    for (int i = t; i < CIN * COUT; i += 256) {
        int k = i >> 6, c = i & 63;
        int byte = (c << 8) + (k << 1);
        byte ^= (c & 7) << 4;
        *(u16*)((char*)Wt + byte) = bf16rne(W[i]);
    }
    __syncthreads();

    f32x4 acc[2][4];
    #pragma unroll
    for (int mt = 0; mt < 2; ++mt)
        #pragma unroll
        for (int nt = 0; nt < 4; ++nt)
            acc[mt][nt] = (f32x4){0.0f, 0.0f, 0.0f, 0.0f};

    #pragma unroll
    for (int kk = 0; kk < 4; ++kk) {
        bf16x8 a[2], bfr[4];
        #pragma unroll
        for (int mt = 0; mt < 2; ++mt) {
            int row = row0 + mt * 16 + cl;
            const float* xp = X + (size_t)(row < n ? row : 0) * CIN + kk * 32 + q * 8;
            f32x4 x0 = __builtin_nontemporal_load((const f32x4*)xp);
            f32x4 x1 = __builtin_nontemporal_load((const f32x4*)(xp + 4));
            B8 pk;
            pk.u[0] = (u32)bf16rne(x0[0]) | ((u32)bf16rne(x0[1]) << 16);
            pk.u[1] = (u32)bf16rne(x0[2]) | ((u32)bf16rne(x0[3]) << 16);
            pk.u[2] = (u32)bf16rne(x1[0]) | ((u32)bf16rne(x1[1]) << 16);
            pk.u[3] = (u32)bf16rne(x1[2]) | ((u32)bf16rne(x1[3]) << 16);
            a[mt] = pk.v;
        }
        #pragma unroll
        for (int nt = 0; nt < 4; ++nt) {
            int c = nt * 16 + cl;
            int byte = (c << 8) + ((kk * 32 + q * 8) << 1);
            byte ^= (c & 7) << 4;
            B8 pk;
            pk.q = *(const uint4*)((const char*)Wt + byte);
            bfr[nt] = pk.v;
        }
        #pragma unroll
        for (int mt = 0; mt < 2; ++mt)
            #pragma unroll
            for (int nt = 0; nt < 4; ++nt)
                acc[mt][nt] = __builtin_amdgcn_mfma_f32_16x16x32_bf16(
                    a[mt], bfr[nt], acc[mt][nt], 0, 0, 0);
    }

    #pragma unroll
    for (int mt = 0; mt < 2; ++mt) {
        const int rbase = row0 + mt * 16 + q * 4;
        float dv[4];
        #pragma unroll
        for (int r = 0; r < 4; ++r)
            dv[r] = (rbase + r < n) ? dinv[rbase + r] : 0.0f;
        #pragma unroll
        for (int nt = 0; nt < 4; ++nt) {
            const int col = nt * 16 + cl;
            const float bc = bias[col];
            #pragma unroll
            for (int r = 0; r < 4; ++r) {
                int row = rbase + r;
                if (row < n)
                    Hs[(size_t)row * COUT + col] = bf16rne((acc[mt][nt][r] + bc) * dv[r]);
            }
        }
    }
}

// ---------------- gatherB: stage + node-sort in LDS, register accumulation ----------------
// Block = bucket (256 nodes). Phases: (1) column tables + chunk scan; (2) copy
// runs -> stage LDS; (3) node hist; (4) node scan; (5) place -> sorted LDS;
// (6) 8 waves x 8 slots, one node per 8-lane slot, reg-accumulate bf16x8 rows.

__global__ __launch_bounds__(512) void gatherB_kernel(
    const u16* __restrict__ Hs, const int* __restrict__ tmp,
    const int* __restrict__ cnt, const int* __restrict__ rowoff,
    const float* __restrict__ dinv, float* __restrict__ out, int n, int nchunk) {
    __shared__ int cntsh[CS];
    __shared__ int crosh[CS];
    __shared__ int dbsh[CS];
    __shared__ int scn[CS];
    __shared__ int stage[BMAX];
    __shared__ int sorted[BMAX];
    __shared__ int nhist[1 << NBSH];
    __shared__ int noff[1 << NBSH];
    __shared__ int ncur[1 << NBSH];
    __shared__ int totsh;
    const int k = blockIdx.x;
    const int t = threadIdx.x;

    // (1) column tables (L2-resident) + chunk scan
    int myc = (t < nchunk) ? cnt[t * CS + k] : 0;
    cntsh[t] = myc;
    crosh[t] = (t < nchunk) ? rowoff[t * CS + k] : 0;
    if (t < (1 << NBSH)) { nhist[t] = 0; ncur[t] = 0; }
    scn[t] = myc;
    __syncthreads();
    #pragma unroll
    for (int ofs = 1; ofs < CS; ofs <<= 1) {
        int u = (t >= ofs) ? scn[t - ofs] : 0;
        __syncthreads();
        scn[t] += u;
        __syncthreads();
    }
    dbsh[t] = scn[t] - myc;
    if (t == CS - 1) totsh = (scn[t] < BMAX) ? scn[t] : BMAX;
    __syncthreads();
    const int total = totsh;

    // (2) copy runs into stage: quarter-wave per chunk-run
    {
        const int qw = t >> 4;
        const int ql = t & 15;
        for (int c = qw; c < nchunk; c += 32) {
            int rc = cntsh[c];
            int sb = c * CHUNK + crosh[c];
            int db = dbsh[c];
            for (int j = ql; j < rc; j += 16) {
                int idx = db + j;
                if (idx < BMAX) stage[idx] = tmp[sb + j];
            }
        }
    }
    __syncthreads();

    // (3) node histogram
    for (int i = t; i < total; i += 512)
        atomicAdd(&nhist[stage[i] & ((1 << NBSH) - 1)], 1);
    __syncthreads();

    // (4) node scan (first 256 lanes meaningful)
    int myv = (t < (1 << NBSH)) ? nhist[t] : 0;
    scn[t] = myv;
    __syncthreads();
    #pragma unroll
    for (int ofs = 1; ofs < CS; ofs <<= 1) {
        int u = (t >= ofs) ? scn[t - ofs] : 0;
        __syncthreads();
        scn[t] += u;
        __syncthreads();
    }
    if (t < (1 << NBSH)) noff[t] = scn[t] - myv;
    __syncthreads();

    // (5) place into node-sorted order
    for (int i = t; i < total; i += 512) {
        int e = stage[i];
        int l = e & ((1 << NBSH) - 1);
        int pos = noff[l] + atomicAdd(&ncur[l], 1);
        sorted[pos] = e >> NBSH;
    }
    __syncthreads();

    // (6) per-node register gather: wave wv, slot (8 lanes) per node
    const int wv = t >> 6;        // 0..7
    const int lane = t & 63;
    const int slot = lane >> 3;   // 0..7
    const int g = lane & 7;       // channel group: ch g*8 .. g*8+7
    #pragma unroll
    for (int r = 0; r < 4; ++r) {
        const int l = (wv << 5) + (r << 3) + slot;
        const int v = (k << NBSH) + l;
        const bool act = v < n;
        const int dcnt = act ? nhist[l] : 0;
        const int o0 = act ? noff[l] : 0;
        float a0 = 0, a1 = 0, a2 = 0, a3 = 0, a4 = 0, a5 = 0, a6 = 0, a7 = 0;
        for (int it = 0; it < dcnt; ++it) {
            int s = sorted[o0 + it];           // 8-lane broadcast read
            uint4 q = *(const uint4*)&Hs[(size_t)s * COUT + g * 8];
            a0 += __uint_as_float(q.x << 16); a1 += __uint_as_float(q.x & 0xffff0000u);
            a2 += __uint_as_float(q.y << 16); a3 += __uint_as_float(q.y & 0xffff0000u);
            a4 += __uint_as_float(q.z << 16); a5 += __uint_as_float(q.z & 0xffff0000u);
            a6 += __uint_as_float(q.w << 16); a7 += __uint_as_float(q.w & 0xffff0000u);
        }
        if (act) {
            uint4 q = *(const uint4*)&Hs[(size_t)v * COUT + g * 8];
            float dv = dinv[v];
            f32x4 o0v, o1v;
            o0v[0] = fmaxf((a0 + __uint_as_float(q.x << 16)) * dv, 0.0f);
            o0v[1] = fmaxf((a1 + __uint_as_float(q.x & 0xffff0000u)) * dv, 0.0f);
            o0v[2] = fmaxf((a2 + __uint_as_float(q.y << 16)) * dv, 0.0f);
            o0v[3] = fmaxf((a3 + __uint_as_float(q.y & 0xffff0000u)) * dv, 0.0f);
            o1v[0] = fmaxf((a4 + __uint_as_float(q.z << 16)) * dv, 0.0f);
            o1v[1] = fmaxf((a5 + __uint_as_float(q.z & 0xffff0000u)) * dv, 0.0f);
            o1v[2] = fmaxf((a6 + __uint_as_float(q.w << 16)) * dv, 0.0f);
            o1v[3] = fmaxf((a7 + __uint_as_float(q.w & 0xffff0000u)) * dv, 0.0f);
            float* op = &out[(size_t)v * COUT + g * 8];
            __builtin_nontemporal_store(o0v, (f32x4*)op);
            __builtin_nontemporal_store(o1v, (f32x4*)(op + 4));
        }
    }
}

extern "C" void kernel_launch(void* const* d_in, const int* in_sizes, int n_in,
                              void* d_out, int out_size, void* d_ws, size_t ws_size,
                              hipStream_t stream) {
    const float* X    = (const float*)d_in[0];
    const float* W    = (const float*)d_in[1];
    const float* bias = (const float*)d_in[2];
    const int*   src  = (const int*)d_in[3];
    const int*   dst  = (const int*)d_in[4];
    float* out = (float*)d_out;

    const int n = in_sizes[0] / CIN;
    const int E = in_sizes[3];
    const int nbk = (n + (1 << NBSH) - 1) >> NBSH;       // <= 512
    const int nchunk = (E + CHUNK - 1) / CHUNK;          // <= 512

    char* ws = (char*)d_ws;
    size_t o = 0;
    u16*   Hs     = (u16*)(ws + o);   o += (size_t)n * COUT * 2;        // 12.8 MB
    int*   tmp    = (int*)(ws + o);   o += (size_t)nchunk * CHUNK * 4;  // 6.4 MB
    int*   cnt    = (int*)(ws + o);   o += (size_t)nchunk * CS * 4;     // 0.8 MB
    int*   rowoff = (int*)(ws + o);   o += (size_t)nchunk * CS * 4;     // 0.8 MB
    float* dinv   = (float*)(ws + o); o += (size_t)n * 4;

    bucket_local_kernel<<<nchunk, 512, 0, stream>>>(src, dst, tmp, cnt, rowoff, E);
    degB_kernel<<<nbk, 512, 0, stream>>>(tmp, cnt, rowoff, dinv, n, nchunk);
    gemm_kernel<<<(n + 127) / 128, 256, 0, stream>>>(X, W, bias, dinv, Hs, n);
    gatherB_kernel<<<nbk, 512, 0, stream>>>(Hs, tmp, cnt, rowoff, dinv, out, n, nchunk);
}